// Round 13
// baseline (345.000 us; speedup 1.0000x reference)
//
#include <hip/hip_runtime.h>
#include <math.h>

typedef __attribute__((ext_vector_type(4))) float f32x4;
typedef __attribute__((ext_vector_type(4))) float f4;
typedef __attribute__((ext_vector_type(8))) _Float16 h8;
typedef __attribute__((ext_vector_type(8))) unsigned short us8;

static __device__ __forceinline__ h8 ld8h(const _Float16* p) {
    return __builtin_bit_cast(h8, *(const us8*)p);
}
static __device__ __forceinline__ void glds16(const void* g, void* l) {
    __builtin_amdgcn_global_load_lds((const __attribute__((address_space(1))) unsigned int*)g,
                                     (__attribute__((address_space(3))) unsigned int*)l, 16, 0, 0);
}

// ---------------------------------------------------------------------------
// fp32 -> fp16, 8 elements/thread
// ---------------------------------------------------------------------------
__global__ void convert_half(const float* __restrict__ in, _Float16* __restrict__ out, int n8) {
    int i = blockIdx.x * blockDim.x + threadIdx.x;
    if (i >= n8) return;
    f4 v0 = *(const f4*)(in + (size_t)i * 8);
    f4 v1 = *(const f4*)(in + (size_t)i * 8 + 4);
    h8 o;
#pragma unroll
    for (int j = 0; j < 4; j++) {
        o[j] = (_Float16)v0[j];
        o[j + 4] = (_Float16)v1[j];
    }
    *(h8*)(out + (size_t)i * 8) = o;
}

// ---------------------------------------------------------------------------
// SuRoPE cos/sin table
// ---------------------------------------------------------------------------
__global__ void rope_table(const float* __restrict__ sf, float* __restrict__ cs,
                           float* __restrict__ sn, float rope_scale) {
    int i = blockIdx.x * blockDim.x + threadIdx.x;  // 2048*48
    const int j = i % 48, l = i / 48;
    const float e = (float)(2 * j) / 96.0f;
    const float inv = 1.0f / (sf[j] * powf(10000.0f, e));
    const float ang = (float)l * inv;
    cs[i] = cosf(ang) * rope_scale;
    sn[i] = sinf(ang) * rope_scale;
}

// ---------------------------------------------------------------------------
// QKV GEMM with fused SuRoPE + head-split epilogue. BM=128, BN=192,
// grid 48x16 = 768 blocks = exactly 3/CU. (MfmaUtil 37% = m97 ceiling.)
// ---------------------------------------------------------------------------
__global__ __launch_bounds__(256, 3) void gemm_qkv(
    const _Float16* __restrict__ A, const _Float16* __restrict__ B,
    const float* __restrict__ cs, const float* __restrict__ sn,
    _Float16* __restrict__ Qh, _Float16* __restrict__ Kh, _Float16* __restrict__ Vh,
    float attn_scale) {
    const int K = 3072;
    __shared__ _Float16 As[2][128][32], Bs[2][192][32];
    const int t = threadIdx.x;
    const int lane = t & 63, w = t >> 6;
    const int bm = blockIdx.y * 128, bn = blockIdx.x * 192;
    const int wm = w >> 1, wn = w & 1;
    const int l15 = lane & 15, l4 = lane >> 4;

    int car[2], cas[2], cbr[3], cbs[3];
#pragma unroll
    for (int i = 0; i < 2; i++) {
        const int c = t + i * 256;
        car[i] = c >> 2;
        cas[i] = (((c & 3) ^ ((car[i] >> 1) & 3)) * 8);
    }
#pragma unroll
    for (int i = 0; i < 3; i++) {
        const int c = t + i * 256;
        cbr[i] = c >> 2;
        cbs[i] = (((c & 3) ^ ((cbr[i] >> 1) & 3)) * 8);
    }

    f32x4 acc[4][6] = {};

#define STG_QKV(k0_, buf)                                                              \
    {                                                                                  \
        _Float16* ab = &As[(buf)][0][0];                                               \
        _Float16* bb = &Bs[(buf)][0][0];                                               \
        _Pragma("unroll") for (int i = 0; i < 2; i++)                                  \
            glds16(A + (size_t)(bm + car[i]) * K + (k0_) + cas[i], ab + (t + i * 256) * 8); \
        _Pragma("unroll") for (int i = 0; i < 3; i++)                                  \
            glds16(B + (size_t)(bn + cbr[i]) * K + (k0_) + cbs[i], bb + (t + i * 256) * 8); \
    }

    STG_QKV(0, 0)

    int cur = 0;
    for (int k0 = 0; k0 < K; k0 += 32) {
        __syncthreads();
        if (k0 + 32 < K) STG_QKV(k0 + 32, cur ^ 1)
        h8 af[4], bf[6];
#pragma unroll
        for (int m = 0; m < 4; m++) {
            const int row = wm * 64 + m * 16 + l15;
            af[m] = ld8h(&As[cur][row][(l4 ^ ((row >> 1) & 3)) * 8]);
        }
#pragma unroll
        for (int n = 0; n < 6; n++) {
            const int row = wn * 96 + n * 16 + l15;
            bf[n] = ld8h(&Bs[cur][row][(l4 ^ ((row >> 1) & 3)) * 8]);
        }
#pragma unroll
        for (int m = 0; m < 4; m++)
#pragma unroll
            for (int n = 0; n < 6; n++)
                acc[m][n] = __builtin_amdgcn_mfma_f32_16x16x32_f16(af[m], bf[n], acc[m][n], 0, 0, 0);
        cur ^= 1;
    }
#undef STG_QKV

    const int opcol0 = bn + wn * 96;
    const int which = opcol0 / 3072;
    const int h = (opcol0 % 3072) / 96;

    if (which == 2) {
#pragma unroll
        for (int m = 0; m < 4; m++)
#pragma unroll
            for (int r = 0; r < 4; r++) {
                const int l = bm + wm * 64 + m * 16 + l4 * 4 + r;
#pragma unroll
                for (int n = 0; n < 6; n++)
                    Vh[((size_t)h * 2048 + l) * 96 + n * 16 + l15] = (_Float16)acc[m][n][r];
            }
    } else {
        _Float16* dst = (which == 0) ? Qh : Kh;
        const float qs = (which == 0) ? attn_scale : 1.0f;
#pragma unroll
        for (int m = 0; m < 4; m++)
#pragma unroll
            for (int r = 0; r < 4; r++) {
                const int l = bm + wm * 64 + m * 16 + l4 * 4 + r;
                const float* csl = cs + l * 48;
                const float* snl = sn + l * 48;
                const size_t rowb = ((size_t)h * 2048 + l) * 96;
#pragma unroll
                for (int n = 0; n < 3; n++) {
                    const int j = n * 16 + l15;
                    const float c = csl[j], s = snl[j];
                    const float lo = acc[m][n][r], hi = acc[m][n + 3][r];
                    dst[rowb + j] = (_Float16)((lo * c - hi * s) * qs);
                    dst[rowb + j + 48] = (_Float16)((hi * c + lo * s) * qs);
                }
            }
    }
}

// ---------------------------------------------------------------------------
// Projection GEMM: BM=128, BN=96, grid 32x16 = 512 blocks = uniform 2/CU.
// ---------------------------------------------------------------------------
__global__ __launch_bounds__(256, 3) void gemm_p(
    const _Float16* __restrict__ A, const _Float16* __restrict__ B,
    float* __restrict__ C, int M, int N, int K) {
    __shared__ _Float16 As[2][128][32], Bs[2][96][32];
    const int t = threadIdx.x;
    const int lane = t & 63, w = t >> 6;
    const int bm = blockIdx.y * 128, bn = blockIdx.x * 96;
    const int wy = w >> 1, wx = w & 1;
    const int l15 = lane & 15, l4 = lane >> 4;

    int car[2], cas[2];
#pragma unroll
    for (int i = 0; i < 2; i++) {
        const int c = t + i * 256;
        car[i] = c >> 2;
        cas[i] = (((c & 3) ^ ((car[i] >> 1) & 3)) * 8);
    }
    const int cb0 = t, rb0 = cb0 >> 2, sb0 = (((cb0 & 3) ^ ((rb0 >> 1) & 3)) * 8);
    const int cb1 = t + 256, rb1 = cb1 >> 2, sb1 = (((cb1 & 3) ^ ((rb1 >> 1) & 3)) * 8);
    const bool bex = (t < 128);

    f32x4 acc[4][3] = {};

#define STG_P(k0_, buf)                                                                \
    {                                                                                  \
        _Float16* ab = &As[(buf)][0][0];                                               \
        _Float16* bb = &Bs[(buf)][0][0];                                               \
        _Pragma("unroll") for (int i = 0; i < 2; i++)                                  \
            glds16(A + (size_t)(bm + car[i]) * K + (k0_) + cas[i], ab + (t + i * 256) * 8); \
        glds16(B + (size_t)(bn + rb0) * K + (k0_) + sb0, bb + cb0 * 8);                \
        if (bex) glds16(B + (size_t)(bn + rb1) * K + (k0_) + sb1, bb + cb1 * 8);       \
    }

    STG_P(0, 0)

    int cur = 0;
    for (int k0 = 0; k0 < K; k0 += 32) {
        __syncthreads();
        if (k0 + 32 < K) STG_P(k0 + 32, cur ^ 1)
        h8 af[4], bf[3];
#pragma unroll
        for (int m = 0; m < 4; m++) {
            const int row = wy * 64 + m * 16 + l15;
            af[m] = ld8h(&As[cur][row][(l4 ^ ((row >> 1) & 3)) * 8]);
        }
#pragma unroll
        for (int n = 0; n < 3; n++) {
            const int row = wx * 48 + n * 16 + l15;
            bf[n] = ld8h(&Bs[cur][row][(l4 ^ ((row >> 1) & 3)) * 8]);
        }
#pragma unroll
        for (int m = 0; m < 4; m++)
#pragma unroll
            for (int n = 0; n < 3; n++)
                acc[m][n] = __builtin_amdgcn_mfma_f32_16x16x32_f16(af[m], bf[n], acc[m][n], 0, 0, 0);
        cur ^= 1;
    }
#undef STG_P

#pragma unroll
    for (int m = 0; m < 4; m++)
#pragma unroll
        for (int n = 0; n < 3; n++)
#pragma unroll
            for (int r = 0; r < 4; r++)
                C[(size_t)(bm + wy * 64 + m * 16 + l4 * 4 + r) * N + bn + wx * 48 + n * 16 + l15] =
                    acc[m][n][r];
}

// ---------------------------------------------------------------------------
// V transpose: Vh [h][l][96] -> Vt[h][d][l] fp16.
// ---------------------------------------------------------------------------
__global__ __launch_bounds__(256) void vtrans(const _Float16* __restrict__ Vh,
                                              _Float16* __restrict__ Vt) {
    __shared__ _Float16 tile[64][105];
    const int h = blockIdx.y;
    const int l0 = blockIdx.x * 64;
    const int t = threadIdx.x;
#pragma unroll
    for (int i = 0; i < 3; i++) {
        const int v = t + i * 256;
        const int row = v / 12, seg = (v % 12) * 8;
        *(us8*)&tile[row][seg] =
            *(const us8*)(Vh + ((size_t)h * 2048 + l0 + row) * 96 + seg);
    }
    __syncthreads();
#pragma unroll
    for (int i = 0; i < 3; i++) {
        const int v = t + i * 256;
        const int d = v >> 3, lc = v & 7;
        h8 o;
#pragma unroll
        for (int j = 0; j < 8; j++) o[j] = tile[lc * 8 + j][d];
        *(h8*)(Vt + ((size_t)h * 96 + d) * 2048 + l0 + lc * 8) = o;
    }
}

// ---------------------------------------------------------------------------
// Flash attention, fp16 MFMA, diagonal-paired (uniform 34 tiles/block).
// 256 threads = 4 waves x 32 q-rows (2 row-groups of 16): K-frag LDS reads
// shared across 2x rows; V-frags hoisted to registers once per tile
// (were re-read per row-group). LDS reads per 32 rows: 52 -> 28.
// Grid 8x32 = 256 blocks = 2/CU. Defer-max (T13) + deferred l-sum.
// ---------------------------------------------------------------------------
__global__ __launch_bounds__(256, 2) void attn_mfma(
    const _Float16* __restrict__ Qh, const _Float16* __restrict__ Kh,
    const _Float16* __restrict__ Vt, _Float16* __restrict__ Oh) {
    __shared__ _Float16 Ks[2][64][104];
    __shared__ _Float16 Vs[2][96][72];
    __shared__ _Float16 Ps[4][16][72];

    const int h = blockIdx.y;
    const int t = threadIdx.x, lane = t & 63, w = t >> 6;  // w 0..3
    const int l15 = lane & 15, l4 = lane >> 4;

    const _Float16* Kg = Kh + (size_t)h * 2048 * 96;
    const _Float16* Vg = Vt + (size_t)h * 96 * 2048;

    // staging: K tile 64x96 = 768 chunks, V tile 96x64 = 768 chunks; 3/thread.
    int rK[3], sK[3], rV[3], sV[3];
#pragma unroll
    for (int i = 0; i < 3; i++) {
        const int c = t + i * 256;
        rK[i] = c / 12; sK[i] = (c % 12) * 8;
        rV[i] = c >> 3; sV[i] = (c & 7) * 8;
    }

    for (int ph = 0; ph < 2; ph++) {
        const int qt = ph ? (int)blockIdx.x : 15 - (int)blockIdx.x;
        const int q0 = qt * 128;
        const int wq = q0 + w * 32;  // this wave's first q-row (32 rows)

        h8 qf[2][3];
#pragma unroll
        for (int g = 0; g < 2; g++) {
            const size_t qrow = ((size_t)h * 2048 + wq + g * 16 + l15) * 96;
#pragma unroll
            for (int kc = 0; kc < 3; kc++) qf[g][kc] = ld8h(Qh + qrow + kc * 32 + l4 * 8);
        }

        us8 kreg[3], vreg[3];
#pragma unroll
        for (int i = 0; i < 3; i++) {
            kreg[i] = *(const us8*)(Kg + (size_t)rK[i] * 96 + sK[i]);
            vreg[i] = *(const us8*)(Vg + (size_t)rV[i] * 2048 + sV[i]);
        }

        f32x4 o[2][6] = {};
        float m_i[2][4], l_i[2][4];
#pragma unroll
        for (int g = 0; g < 2; g++)
#pragma unroll
            for (int r = 0; r < 4; r++) { m_i[g][r] = -1e30f; l_i[g][r] = 0.f; }

        const int nkt = 2 * qt + 2;
        for (int kt = 0; kt < nkt; kt++) {
            const int kv0 = kt * 64;
            const int buf = kt & 1;
#pragma unroll
            for (int i = 0; i < 3; i++) {
                *(us8*)&Ks[buf][rK[i]][sK[i]] = kreg[i];
                *(us8*)&Vs[buf][rV[i]][sV[i]] = vreg[i];
            }
            __syncthreads();
            if (kt + 1 < nkt) {  // prefetch next tile into regs (T14)
                const int kv1 = kv0 + 64;
#pragma unroll
                for (int i = 0; i < 3; i++) {
                    kreg[i] = *(const us8*)(Kg + (size_t)(kv1 + rK[i]) * 96 + sK[i]);
                    vreg[i] = *(const us8*)(Vg + (size_t)rV[i] * 2048 + kv1 + sV[i]);
                }
            }

            if (kv0 <= wq + 31) {  // tile visible to this wave
                // S = Q K^T, both row-groups share the 12 K-frag reads
                f32x4 s[2][4] = {};
#pragma unroll
                for (int f = 0; f < 4; f++)
#pragma unroll
                    for (int kc = 0; kc < 3; kc++) {
                        h8 kf = ld8h(&Ks[buf][f * 16 + l15][kc * 32 + l4 * 8]);
#pragma unroll
                        for (int g = 0; g < 2; g++)
                            s[g][f] = __builtin_amdgcn_mfma_f32_16x16x32_f16(qf[g][kc], kf, s[g][f], 0, 0, 0);
                    }

                if (kv0 + 63 > wq) {  // diagonal-crossing: causal mask
#pragma unroll
                    for (int g = 0; g < 2; g++)
#pragma unroll
                        for (int f = 0; f < 4; f++)
#pragma unroll
                            for (int r = 0; r < 4; r++)
                                if (kv0 + f * 16 + l15 > wq + g * 16 + l4 * 4 + r) s[g][f][r] = -1e30f;
                }

                // hoist V-frags to registers once per tile (shared across groups)
                h8 vb[2][6];
#pragma unroll
                for (int kc2 = 0; kc2 < 2; kc2++)
#pragma unroll
                    for (int f2 = 0; f2 < 6; f2++)
                        vb[kc2][f2] = ld8h(&Vs[buf][f2 * 16 + l15][kc2 * 32 + l4 * 8]);

                float mx[2][4];
#pragma unroll
                for (int g = 0; g < 2; g++)
#pragma unroll
                    for (int r = 0; r < 4; r++) {
                        float m0 = fmaxf(fmaxf(s[g][0][r], s[g][1][r]), fmaxf(s[g][2][r], s[g][3][r]));
#pragma unroll
                        for (int msk = 1; msk < 16; msk <<= 1) m0 = fmaxf(m0, __shfl_xor(m0, msk, 64));
                        mx[g][r] = m0;
                    }

                bool need = false;
#pragma unroll
                for (int g = 0; g < 2; g++)
#pragma unroll
                    for (int r = 0; r < 4; r++) need = need || (mx[g][r] > m_i[g][r] + 8.0f);
                if (__any(need)) {
#pragma unroll
                    for (int g = 0; g < 2; g++)
#pragma unroll
                        for (int r = 0; r < 4; r++) {
                            const float mnew = fmaxf(m_i[g][r], mx[g][r]);
                            const float sc = __expf(m_i[g][r] - mnew);
                            m_i[g][r] = mnew;
                            l_i[g][r] *= sc;
#pragma unroll
                            for (int f2 = 0; f2 < 6; f2++) o[g][f2][r] *= sc;
                        }
                }

                // per row-group: P -> per-wave LDS, then PV with reg V-frags
#pragma unroll
                for (int g = 0; g < 2; g++) {
#pragma unroll
                    for (int f = 0; f < 4; f++)
#pragma unroll
                        for (int r = 0; r < 4; r++) {
                            const float p = __expf(s[g][f][r] - m_i[g][r]);
                            Ps[w][l4 * 4 + r][f * 16 + l15] = (_Float16)p;
                            l_i[g][r] += p;  // per-lane partial
                        }
#pragma unroll
                    for (int kc2 = 0; kc2 < 2; kc2++) {
                        h8 pa = ld8h(&Ps[w][l15][kc2 * 32 + l4 * 8]);
#pragma unroll
                        for (int f2 = 0; f2 < 6; f2++)
                            o[g][f2] = __builtin_amdgcn_mfma_f32_16x16x32_f16(pa, vb[kc2][f2], o[g][f2], 0, 0, 0);
                    }
                }
            }
        }

        __syncthreads();  // all waves done with LDS before next phase restages

#pragma unroll
        for (int g = 0; g < 2; g++)
#pragma unroll
            for (int r = 0; r < 4; r++) {
                float ss = l_i[g][r];
#pragma unroll
                for (int msk = 1; msk < 16; msk <<= 1) ss += __shfl_xor(ss, msk, 64);
                const float inv = 1.0f / ss;
                const size_t row = (size_t)(wq + g * 16 + l4 * 4 + r) * 3072 + h * 96;
#pragma unroll
                for (int f2 = 0; f2 < 6; f2++)
                    Oh[row + f2 * 16 + l15] = (_Float16)(o[g][f2][r] * inv);
            }
    }
}

// ---------------------------------------------------------------------------
extern "C" void kernel_launch(void* const* d_in, const int* in_sizes, int n_in,
                              void* d_out, int out_size, void* d_ws, size_t ws_size,
                              hipStream_t stream) {
    const float* x = (const float*)d_in[0];
    const float* w_qkv = (const float*)d_in[1];
    const float* w_o = (const float*)d_in[2];
    const float* sf = (const float*)d_in[3];
    float* out = (float*)d_out;
    char* ws = (char*)d_ws;

    _Float16* wqkvh = (_Float16*)(ws);             // [0, 56.6MB)
    _Float16* Qh = (_Float16*)(ws + 56623104);
    _Float16* Kh = (_Float16*)(ws + 69206016);
    _Float16* Vh = (_Float16*)(ws + 81788928);
    _Float16* Vth = (_Float16*)(ws + 94371840);
    _Float16* Oh = (_Float16*)(ws + 106954752);
    _Float16* xh = (_Float16*)(ws + 132120576);
    _Float16* woh = (_Float16*)(ws + 144703488);
    float* cs = (float*)(ws + 163577856);
    float* sn = (float*)(ws + 163971072);

    const float rope_scale = (float)sqrt(1.0 + log(131072.0 / 4096.0) / log(4096.0));
    const float attn_scale = (float)(1.0 / sqrt(96.0));

    convert_half<<<3072, 256, 0, stream>>>(x, xh, 786432);
    convert_half<<<13824, 256, 0, stream>>>(w_qkv, wqkvh, 3538944);
    rope_table<<<384, 256, 0, stream>>>(sf, cs, sn, rope_scale);
    gemm_qkv<<<dim3(48, 16), 256, 0, stream>>>(xh, wqkvh, cs, sn, Qh, Kh, Vh, attn_scale);
    vtrans<<<dim3(32, 32), 256, 0, stream>>>(Vh, Vth);
    convert_half<<<4608, 256, 0, stream>>>(w_o, woh, 1179648);
    attn_mfma<<<dim3(8, 32), 256, 0, stream>>>(Qh, Kh, Vth, Oh);
    gemm_p<<<dim3(32, 16), 256, 0, stream>>>(Oh, woh, out, 2048, 3072, 3072);
}

// Round 14
// 321.605 us; speedup vs baseline: 1.0727x; 1.0727x over previous
//
#include <hip/hip_runtime.h>
#include <math.h>

typedef __attribute__((ext_vector_type(4))) float f32x4;
typedef __attribute__((ext_vector_type(4))) float f4;
typedef __attribute__((ext_vector_type(8))) _Float16 h8;
typedef __attribute__((ext_vector_type(4))) _Float16 h4;
typedef __attribute__((ext_vector_type(8))) unsigned short us8;

static __device__ __forceinline__ h8 ld8h(const _Float16* p) {
    return __builtin_bit_cast(h8, *(const us8*)p);
}
static __device__ __forceinline__ void glds16(const void* g, void* l) {
    __builtin_amdgcn_global_load_lds((const __attribute__((address_space(1))) unsigned int*)g,
                                     (__attribute__((address_space(3))) unsigned int*)l, 16, 0, 0);
}

// ---------------------------------------------------------------------------
// fp32 -> fp16, 8 elements/thread
// ---------------------------------------------------------------------------
__global__ void convert_half(const float* __restrict__ in, _Float16* __restrict__ out, int n8) {
    int i = blockIdx.x * blockDim.x + threadIdx.x;
    if (i >= n8) return;
    f4 v0 = *(const f4*)(in + (size_t)i * 8);
    f4 v1 = *(const f4*)(in + (size_t)i * 8 + 4);
    h8 o;
#pragma unroll
    for (int j = 0; j < 4; j++) {
        o[j] = (_Float16)v0[j];
        o[j + 4] = (_Float16)v1[j];
    }
    *(h8*)(out + (size_t)i * 8) = o;
}

// ---------------------------------------------------------------------------
// SuRoPE cos/sin table
// ---------------------------------------------------------------------------
__global__ void rope_table(const float* __restrict__ sf, float* __restrict__ cs,
                           float* __restrict__ sn, float rope_scale) {
    int i = blockIdx.x * blockDim.x + threadIdx.x;  // 2048*48
    const int j = i % 48, l = i / 48;
    const float e = (float)(2 * j) / 96.0f;
    const float inv = 1.0f / (sf[j] * powf(10000.0f, e));
    const float ang = (float)l * inv;
    cs[i] = cosf(ang) * rope_scale;
    sn[i] = sinf(ang) * rope_scale;
}

// ---------------------------------------------------------------------------
// QKV GEMM, fused SuRoPE + head-split + V-TRANSPOSE epilogue. BM=128, BN=192,
// grid 48x16 = 768 blocks = exactly 3/CU. V waves write Vt[h][d][l] directly
// (per-lane 8B us4 store: rows l4*4+r are consecutive l) — vtrans kernel gone.
// ---------------------------------------------------------------------------
__global__ __launch_bounds__(256, 3) void gemm_qkv(
    const _Float16* __restrict__ A, const _Float16* __restrict__ B,
    const float* __restrict__ cs, const float* __restrict__ sn,
    _Float16* __restrict__ Qh, _Float16* __restrict__ Kh, _Float16* __restrict__ Vt,
    float attn_scale) {
    const int K = 3072;
    __shared__ _Float16 As[2][128][32], Bs[2][192][32];
    const int t = threadIdx.x;
    const int lane = t & 63, w = t >> 6;
    const int bm = blockIdx.y * 128, bn = blockIdx.x * 192;
    const int wm = w >> 1, wn = w & 1;
    const int l15 = lane & 15, l4 = lane >> 4;

    int car[2], cas[2], cbr[3], cbs[3];
#pragma unroll
    for (int i = 0; i < 2; i++) {
        const int c = t + i * 256;
        car[i] = c >> 2;
        cas[i] = (((c & 3) ^ ((car[i] >> 1) & 3)) * 8);
    }
#pragma unroll
    for (int i = 0; i < 3; i++) {
        const int c = t + i * 256;
        cbr[i] = c >> 2;
        cbs[i] = (((c & 3) ^ ((cbr[i] >> 1) & 3)) * 8);
    }

    f32x4 acc[4][6] = {};

#define STG_QKV(k0_, buf)                                                              \
    {                                                                                  \
        _Float16* ab = &As[(buf)][0][0];                                               \
        _Float16* bb = &Bs[(buf)][0][0];                                               \
        _Pragma("unroll") for (int i = 0; i < 2; i++)                                  \
            glds16(A + (size_t)(bm + car[i]) * K + (k0_) + cas[i], ab + (t + i * 256) * 8); \
        _Pragma("unroll") for (int i = 0; i < 3; i++)                                  \
            glds16(B + (size_t)(bn + cbr[i]) * K + (k0_) + cbs[i], bb + (t + i * 256) * 8); \
    }

    STG_QKV(0, 0)

    int cur = 0;
    for (int k0 = 0; k0 < K; k0 += 32) {
        __syncthreads();
        if (k0 + 32 < K) STG_QKV(k0 + 32, cur ^ 1)
        h8 af[4], bf[6];
#pragma unroll
        for (int m = 0; m < 4; m++) {
            const int row = wm * 64 + m * 16 + l15;
            af[m] = ld8h(&As[cur][row][(l4 ^ ((row >> 1) & 3)) * 8]);
        }
#pragma unroll
        for (int n = 0; n < 6; n++) {
            const int row = wn * 96 + n * 16 + l15;
            bf[n] = ld8h(&Bs[cur][row][(l4 ^ ((row >> 1) & 3)) * 8]);
        }
#pragma unroll
        for (int m = 0; m < 4; m++)
#pragma unroll
            for (int n = 0; n < 6; n++)
                acc[m][n] = __builtin_amdgcn_mfma_f32_16x16x32_f16(af[m], bf[n], acc[m][n], 0, 0, 0);
        cur ^= 1;
    }
#undef STG_QKV

    const int opcol0 = bn + wn * 96;
    const int which = opcol0 / 3072;
    const int h = (opcol0 % 3072) / 96;

    if (which == 2) {
        // fused transpose: Vt[h][d][l], d = n*16+l15, l = bm+wm*64+m*16+l4*4+r
#pragma unroll
        for (int m = 0; m < 4; m++)
#pragma unroll
            for (int n = 0; n < 6; n++) {
                h4 v;
#pragma unroll
                for (int r = 0; r < 4; r++) v[r] = (_Float16)acc[m][n][r];
                *(h4*)(Vt + ((size_t)h * 96 + n * 16 + l15) * 2048 + bm + wm * 64 + m * 16 + l4 * 4) = v;
            }
    } else {
        _Float16* dst = (which == 0) ? Qh : Kh;
        const float qs = (which == 0) ? attn_scale : 1.0f;
#pragma unroll
        for (int m = 0; m < 4; m++)
#pragma unroll
            for (int r = 0; r < 4; r++) {
                const int l = bm + wm * 64 + m * 16 + l4 * 4 + r;
                const float* csl = cs + l * 48;
                const float* snl = sn + l * 48;
                const size_t rowb = ((size_t)h * 2048 + l) * 96;
#pragma unroll
                for (int n = 0; n < 3; n++) {
                    const int j = n * 16 + l15;
                    const float c = csl[j], s = snl[j];
                    const float lo = acc[m][n][r], hi = acc[m][n + 3][r];
                    dst[rowb + j] = (_Float16)((lo * c - hi * s) * qs);
                    dst[rowb + j + 48] = (_Float16)((hi * c + lo * s) * qs);
                }
            }
    }
}

// ---------------------------------------------------------------------------
// Projection GEMM: BM=128, BN=96, grid 32x16 = 512 blocks = uniform 2/CU.
// ---------------------------------------------------------------------------
__global__ __launch_bounds__(256, 3) void gemm_p(
    const _Float16* __restrict__ A, const _Float16* __restrict__ B,
    float* __restrict__ C, int M, int N, int K) {
    __shared__ _Float16 As[2][128][32], Bs[2][96][32];
    const int t = threadIdx.x;
    const int lane = t & 63, w = t >> 6;
    const int bm = blockIdx.y * 128, bn = blockIdx.x * 96;
    const int wy = w >> 1, wx = w & 1;
    const int l15 = lane & 15, l4 = lane >> 4;

    int car[2], cas[2];
#pragma unroll
    for (int i = 0; i < 2; i++) {
        const int c = t + i * 256;
        car[i] = c >> 2;
        cas[i] = (((c & 3) ^ ((car[i] >> 1) & 3)) * 8);
    }
    const int cb0 = t, rb0 = cb0 >> 2, sb0 = (((cb0 & 3) ^ ((rb0 >> 1) & 3)) * 8);
    const int cb1 = t + 256, rb1 = cb1 >> 2, sb1 = (((cb1 & 3) ^ ((rb1 >> 1) & 3)) * 8);
    const bool bex = (t < 128);

    f32x4 acc[4][3] = {};

#define STG_P(k0_, buf)                                                                \
    {                                                                                  \
        _Float16* ab = &As[(buf)][0][0];                                               \
        _Float16* bb = &Bs[(buf)][0][0];                                               \
        _Pragma("unroll") for (int i = 0; i < 2; i++)                                  \
            glds16(A + (size_t)(bm + car[i]) * K + (k0_) + cas[i], ab + (t + i * 256) * 8); \
        glds16(B + (size_t)(bn + rb0) * K + (k0_) + sb0, bb + cb0 * 8);                \
        if (bex) glds16(B + (size_t)(bn + rb1) * K + (k0_) + sb1, bb + cb1 * 8);       \
    }

    STG_P(0, 0)

    int cur = 0;
    for (int k0 = 0; k0 < K; k0 += 32) {
        __syncthreads();
        if (k0 + 32 < K) STG_P(k0 + 32, cur ^ 1)
        h8 af[4], bf[3];
#pragma unroll
        for (int m = 0; m < 4; m++) {
            const int row = wy * 64 + m * 16 + l15;
            af[m] = ld8h(&As[cur][row][(l4 ^ ((row >> 1) & 3)) * 8]);
        }
#pragma unroll
        for (int n = 0; n < 3; n++) {
            const int row = wx * 48 + n * 16 + l15;
            bf[n] = ld8h(&Bs[cur][row][(l4 ^ ((row >> 1) & 3)) * 8]);
        }
#pragma unroll
        for (int m = 0; m < 4; m++)
#pragma unroll
            for (int n = 0; n < 3; n++)
                acc[m][n] = __builtin_amdgcn_mfma_f32_16x16x32_f16(af[m], bf[n], acc[m][n], 0, 0, 0);
        cur ^= 1;
    }
#undef STG_P

#pragma unroll
    for (int m = 0; m < 4; m++)
#pragma unroll
        for (int n = 0; n < 3; n++)
#pragma unroll
            for (int r = 0; r < 4; r++)
                C[(size_t)(bm + wy * 64 + m * 16 + l4 * 4 + r) * N + bn + wx * 48 + n * 16 + l15] =
                    acc[m][n][r];
}

// ---------------------------------------------------------------------------
// Flash attention, fp16 MFMA, diagonal-paired (uniform 17 tiles per phase-
// pair, 256 blocks). R12 structure: 512 thr = 8 waves x 16 q-rows, KV tiles
// of 64, dbuf + async reg-staging, defer-max, deferred l-sum. + T5 setprio.
// ---------------------------------------------------------------------------
__global__ __launch_bounds__(512, 2) void attn_mfma(
    const _Float16* __restrict__ Qh, const _Float16* __restrict__ Kh,
    const _Float16* __restrict__ Vt, _Float16* __restrict__ Oh) {
    __shared__ _Float16 Ks[2][64][104];
    __shared__ _Float16 Vs[2][96][72];
    __shared__ _Float16 Ps[8][16][72];

    const int h = blockIdx.y;
    const int t = threadIdx.x, lane = t & 63, w = t >> 6;
    const int l15 = lane & 15, l4 = lane >> 4;

    const _Float16* Kg = Kh + (size_t)h * 2048 * 96;
    const _Float16* Vg = Vt + (size_t)h * 96 * 2048;

    const int cA = t, rKA = cA / 12, sKA = (cA % 12) * 8;
    const int rVA = cA >> 3, sVA = (cA & 7) * 8;
    const int cB = 512 + t, rKB = cB / 12, sKB = (cB % 12) * 8;
    const int rVB = cB >> 3, sVB = (cB & 7) * 8;
    const bool two = (t < 256);

    for (int ph = 0; ph < 2; ph++) {
        const int qt = ph ? (int)blockIdx.x : 15 - (int)blockIdx.x;
        const int q0 = qt * 128;
        const int wq = q0 + w * 16;

        h8 qf[3];
        const size_t qrow = ((size_t)h * 2048 + wq + l15) * 96;
#pragma unroll
        for (int kc = 0; kc < 3; kc++) qf[kc] = ld8h(Qh + qrow + kc * 32 + l4 * 8);

        us8 kregA, vregA, kregB, vregB;
        kregA = *(const us8*)(Kg + (size_t)rKA * 96 + sKA);
        vregA = *(const us8*)(Vg + (size_t)rVA * 2048 + sVA);
        if (two) {
            kregB = *(const us8*)(Kg + (size_t)rKB * 96 + sKB);
            vregB = *(const us8*)(Vg + (size_t)rVB * 2048 + sVB);
        }

        f32x4 o[6] = {};
        float m_i[4] = {-1e30f, -1e30f, -1e30f, -1e30f};
        float l_i[4] = {0.f, 0.f, 0.f, 0.f};

        const int nkt = 2 * qt + 2;
        for (int kt = 0; kt < nkt; kt++) {
            const int kv0 = kt * 64;
            const int buf = kt & 1;
            *(us8*)&Ks[buf][rKA][sKA] = kregA;
            *(us8*)&Vs[buf][rVA][sVA] = vregA;
            if (two) {
                *(us8*)&Ks[buf][rKB][sKB] = kregB;
                *(us8*)&Vs[buf][rVB][sVB] = vregB;
            }
            __syncthreads();
            if (kt + 1 < nkt) {  // prefetch next tile into regs (T14)
                const int kv1 = kv0 + 64;
                kregA = *(const us8*)(Kg + (size_t)(kv1 + rKA) * 96 + sKA);
                vregA = *(const us8*)(Vg + (size_t)rVA * 2048 + kv1 + sVA);
                if (two) {
                    kregB = *(const us8*)(Kg + (size_t)(kv1 + rKB) * 96 + sKB);
                    vregB = *(const us8*)(Vg + (size_t)rVB * 2048 + kv1 + sVB);
                }
            }

            if (kv0 <= wq + 15) {  // tile visible to this wave
                f32x4 s[4] = {};
                __builtin_amdgcn_s_setprio(1);
#pragma unroll
                for (int f = 0; f < 4; f++)
#pragma unroll
                    for (int kc = 0; kc < 3; kc++) {
                        h8 kf = ld8h(&Ks[buf][f * 16 + l15][kc * 32 + l4 * 8]);
                        s[f] = __builtin_amdgcn_mfma_f32_16x16x32_f16(qf[kc], kf, s[f], 0, 0, 0);
                    }
                __builtin_amdgcn_s_setprio(0);

                if (kv0 + 63 > wq) {  // diagonal-crossing: causal mask
#pragma unroll
                    for (int f = 0; f < 4; f++)
#pragma unroll
                        for (int r = 0; r < 4; r++)
                            if (kv0 + f * 16 + l15 > wq + l4 * 4 + r) s[f][r] = -1e30f;
                }

                float mx[4];
#pragma unroll
                for (int r = 0; r < 4; r++) {
                    float m0 = fmaxf(fmaxf(s[0][r], s[1][r]), fmaxf(s[2][r], s[3][r]));
#pragma unroll
                    for (int msk = 1; msk < 16; msk <<= 1) m0 = fmaxf(m0, __shfl_xor(m0, msk, 64));
                    mx[r] = m0;
                }

                bool need = false;
#pragma unroll
                for (int r = 0; r < 4; r++) need = need || (mx[r] > m_i[r] + 8.0f);
                if (__any(need)) {
#pragma unroll
                    for (int r = 0; r < 4; r++) {
                        const float mnew = fmaxf(m_i[r], mx[r]);
                        const float sc = __expf(m_i[r] - mnew);
                        m_i[r] = mnew;
                        l_i[r] *= sc;
#pragma unroll
                        for (int f2 = 0; f2 < 6; f2++) o[f2][r] *= sc;
                    }
                }

#pragma unroll
                for (int f = 0; f < 4; f++)
#pragma unroll
                    for (int r = 0; r < 4; r++) {
                        const float p = __expf(s[f][r] - m_i[r]);
                        Ps[w][l4 * 4 + r][f * 16 + l15] = (_Float16)p;
                        l_i[r] += p;  // per-lane partial; reduced in epilogue
                    }
                __builtin_amdgcn_s_setprio(1);
#pragma unroll
                for (int kc2 = 0; kc2 < 2; kc2++) {
                    h8 pa = ld8h(&Ps[w][l15][kc2 * 32 + l4 * 8]);
#pragma unroll
                    for (int f2 = 0; f2 < 6; f2++) {
                        h8 vb = ld8h(&Vs[buf][f2 * 16 + l15][kc2 * 32 + l4 * 8]);
                        o[f2] = __builtin_amdgcn_mfma_f32_16x16x32_f16(pa, vb, o[f2], 0, 0, 0);
                    }
                }
                __builtin_amdgcn_s_setprio(0);
            }
        }

        __syncthreads();  // all waves done with LDS before next phase restages

#pragma unroll
        for (int r = 0; r < 4; r++) {
            float ss = l_i[r];
#pragma unroll
            for (int msk = 1; msk < 16; msk <<= 1) ss += __shfl_xor(ss, msk, 64);
            const float inv = 1.0f / ss;
            const size_t row = (size_t)(wq + l4 * 4 + r) * 3072 + h * 96;
#pragma unroll
            for (int f2 = 0; f2 < 6; f2++)
                Oh[row + f2 * 16 + l15] = (_Float16)(o[f2][r] * inv);
        }
    }
}

// ---------------------------------------------------------------------------
extern "C" void kernel_launch(void* const* d_in, const int* in_sizes, int n_in,
                              void* d_out, int out_size, void* d_ws, size_t ws_size,
                              hipStream_t stream) {
    const float* x = (const float*)d_in[0];
    const float* w_qkv = (const float*)d_in[1];
    const float* w_o = (const float*)d_in[2];
    const float* sf = (const float*)d_in[3];
    float* out = (float*)d_out;
    char* ws = (char*)d_ws;

    _Float16* wqkvh = (_Float16*)(ws);             // [0, 56.6MB)
    _Float16* Qh = (_Float16*)(ws + 56623104);
    _Float16* Kh = (_Float16*)(ws + 69206016);
    _Float16* Vth = (_Float16*)(ws + 81788928);
    _Float16* Oh = (_Float16*)(ws + 94371840);
    _Float16* xh = (_Float16*)(ws + 132120576);
    _Float16* woh = (_Float16*)(ws + 144703488);
    float* cs = (float*)(ws + 163577856);
    float* sn = (float*)(ws + 163971072);

    const float rope_scale = (float)sqrt(1.0 + log(131072.0 / 4096.0) / log(4096.0));
    const float attn_scale = (float)(1.0 / sqrt(96.0));

    convert_half<<<3072, 256, 0, stream>>>(x, xh, 786432);
    convert_half<<<13824, 256, 0, stream>>>(w_qkv, wqkvh, 3538944);
    rope_table<<<384, 256, 0, stream>>>(sf, cs, sn, rope_scale);
    gemm_qkv<<<dim3(48, 16), 256, 0, stream>>>(xh, wqkvh, cs, sn, Qh, Kh, Vth, attn_scale);
    convert_half<<<4608, 256, 0, stream>>>(w_o, woh, 1179648);
    attn_mfma<<<dim3(8, 32), 512, 0, stream>>>(Qh, Kh, Vth, Oh);
    gemm_p<<<dim3(32, 16), 256, 0, stream>>>(Oh, woh, out, 2048, 3072, 3072);
}

// Round 15
// 309.626 us; speedup vs baseline: 1.1142x; 1.0387x over previous
//
#include <hip/hip_runtime.h>
#include <math.h>

typedef __attribute__((ext_vector_type(4))) float f32x4;
typedef __attribute__((ext_vector_type(4))) float f4;
typedef __attribute__((ext_vector_type(8))) _Float16 h8;
typedef __attribute__((ext_vector_type(4))) _Float16 h4;
typedef __attribute__((ext_vector_type(8))) unsigned short us8;

static __device__ __forceinline__ h8 ld8h(const _Float16* p) {
    return __builtin_bit_cast(h8, *(const us8*)p);
}
static __device__ __forceinline__ void glds16(const void* g, void* l) {
    __builtin_amdgcn_global_load_lds((const __attribute__((address_space(1))) unsigned int*)g,
                                     (__attribute__((address_space(3))) unsigned int*)l, 16, 0, 0);
}

// ---------------------------------------------------------------------------
// fp32 -> fp16, 8 elements/thread
// ---------------------------------------------------------------------------
__global__ void convert_half(const float* __restrict__ in, _Float16* __restrict__ out, int n8) {
    int i = blockIdx.x * blockDim.x + threadIdx.x;
    if (i >= n8) return;
    f4 v0 = *(const f4*)(in + (size_t)i * 8);
    f4 v1 = *(const f4*)(in + (size_t)i * 8 + 4);
    h8 o;
#pragma unroll
    for (int j = 0; j < 4; j++) {
        o[j] = (_Float16)v0[j];
        o[j + 4] = (_Float16)v1[j];
    }
    *(h8*)(out + (size_t)i * 8) = o;
}

// ---------------------------------------------------------------------------
// SuRoPE cos/sin table
// ---------------------------------------------------------------------------
__global__ void rope_table(const float* __restrict__ sf, float* __restrict__ cs,
                           float* __restrict__ sn, float rope_scale) {
    int i = blockIdx.x * blockDim.x + threadIdx.x;  // 2048*48
    const int j = i % 48, l = i / 48;
    const float e = (float)(2 * j) / 96.0f;
    const float inv = 1.0f / (sf[j] * powf(10000.0f, e));
    const float ang = (float)l * inv;
    cs[i] = cosf(ang) * rope_scale;
    sn[i] = sinf(ang) * rope_scale;
}

// ---------------------------------------------------------------------------
// QKV GEMM, fused SuRoPE + head-split + V-transpose epilogue. BM=128, BN=192,
// grid 48x16 = 768 blocks = exactly 3/CU. Q is scaled by attn_scale*log2(e)
// so attention uses exp2 directly (v_exp_f32, no mul).
// ---------------------------------------------------------------------------
__global__ __launch_bounds__(256, 3) void gemm_qkv(
    const _Float16* __restrict__ A, const _Float16* __restrict__ B,
    const float* __restrict__ cs, const float* __restrict__ sn,
    _Float16* __restrict__ Qh, _Float16* __restrict__ Kh, _Float16* __restrict__ Vt,
    float q_scale) {
    const int K = 3072;
    __shared__ _Float16 As[2][128][32], Bs[2][192][32];
    const int t = threadIdx.x;
    const int lane = t & 63, w = t >> 6;
    const int bm = blockIdx.y * 128, bn = blockIdx.x * 192;
    const int wm = w >> 1, wn = w & 1;
    const int l15 = lane & 15, l4 = lane >> 4;

    int car[2], cas[2], cbr[3], cbs[3];
#pragma unroll
    for (int i = 0; i < 2; i++) {
        const int c = t + i * 256;
        car[i] = c >> 2;
        cas[i] = (((c & 3) ^ ((car[i] >> 1) & 3)) * 8);
    }
#pragma unroll
    for (int i = 0; i < 3; i++) {
        const int c = t + i * 256;
        cbr[i] = c >> 2;
        cbs[i] = (((c & 3) ^ ((cbr[i] >> 1) & 3)) * 8);
    }

    f32x4 acc[4][6] = {};

#define STG_QKV(k0_, buf)                                                              \
    {                                                                                  \
        _Float16* ab = &As[(buf)][0][0];                                               \
        _Float16* bb = &Bs[(buf)][0][0];                                               \
        _Pragma("unroll") for (int i = 0; i < 2; i++)                                  \
            glds16(A + (size_t)(bm + car[i]) * K + (k0_) + cas[i], ab + (t + i * 256) * 8); \
        _Pragma("unroll") for (int i = 0; i < 3; i++)                                  \
            glds16(B + (size_t)(bn + cbr[i]) * K + (k0_) + cbs[i], bb + (t + i * 256) * 8); \
    }

    STG_QKV(0, 0)

    int cur = 0;
    for (int k0 = 0; k0 < K; k0 += 32) {
        __syncthreads();
        if (k0 + 32 < K) STG_QKV(k0 + 32, cur ^ 1)
        h8 af[4], bf[6];
#pragma unroll
        for (int m = 0; m < 4; m++) {
            const int row = wm * 64 + m * 16 + l15;
            af[m] = ld8h(&As[cur][row][(l4 ^ ((row >> 1) & 3)) * 8]);
        }
#pragma unroll
        for (int n = 0; n < 6; n++) {
            const int row = wn * 96 + n * 16 + l15;
            bf[n] = ld8h(&Bs[cur][row][(l4 ^ ((row >> 1) & 3)) * 8]);
        }
#pragma unroll
        for (int m = 0; m < 4; m++)
#pragma unroll
            for (int n = 0; n < 6; n++)
                acc[m][n] = __builtin_amdgcn_mfma_f32_16x16x32_f16(af[m], bf[n], acc[m][n], 0, 0, 0);
        cur ^= 1;
    }
#undef STG_QKV

    const int opcol0 = bn + wn * 96;
    const int which = opcol0 / 3072;
    const int h = (opcol0 % 3072) / 96;

    if (which == 2) {
        // fused transpose: Vt[h][d][l], d = n*16+l15, l = bm+wm*64+m*16+l4*4+r
#pragma unroll
        for (int m = 0; m < 4; m++)
#pragma unroll
            for (int n = 0; n < 6; n++) {
                h4 v;
#pragma unroll
                for (int r = 0; r < 4; r++) v[r] = (_Float16)acc[m][n][r];
                *(h4*)(Vt + ((size_t)h * 96 + n * 16 + l15) * 2048 + bm + wm * 64 + m * 16 + l4 * 4) = v;
            }
    } else {
        _Float16* dst = (which == 0) ? Qh : Kh;
        const float qs = (which == 0) ? q_scale : 1.0f;
#pragma unroll
        for (int m = 0; m < 4; m++)
#pragma unroll
            for (int r = 0; r < 4; r++) {
                const int l = bm + wm * 64 + m * 16 + l4 * 4 + r;
                const float* csl = cs + l * 48;
                const float* snl = sn + l * 48;
                const size_t rowb = ((size_t)h * 2048 + l) * 96;
#pragma unroll
                for (int n = 0; n < 3; n++) {
                    const int j = n * 16 + l15;
                    const float c = csl[j], s = snl[j];
                    const float lo = acc[m][n][r], hi = acc[m][n + 3][r];
                    dst[rowb + j] = (_Float16)((lo * c - hi * s) * qs);
                    dst[rowb + j + 48] = (_Float16)((hi * c + lo * s) * qs);
                }
            }
    }
}

// ---------------------------------------------------------------------------
// Projection GEMM: BM=128, BN=96, grid 32x16 = 512 blocks = uniform 2/CU.
// ---------------------------------------------------------------------------
__global__ __launch_bounds__(256, 3) void gemm_p(
    const _Float16* __restrict__ A, const _Float16* __restrict__ B,
    float* __restrict__ C, int M, int N, int K) {
    __shared__ _Float16 As[2][128][32], Bs[2][96][32];
    const int t = threadIdx.x;
    const int lane = t & 63, w = t >> 6;
    const int bm = blockIdx.y * 128, bn = blockIdx.x * 96;
    const int wy = w >> 1, wx = w & 1;
    const int l15 = lane & 15, l4 = lane >> 4;

    int car[2], cas[2];
#pragma unroll
    for (int i = 0; i < 2; i++) {
        const int c = t + i * 256;
        car[i] = c >> 2;
        cas[i] = (((c & 3) ^ ((car[i] >> 1) & 3)) * 8);
    }
    const int cb0 = t, rb0 = cb0 >> 2, sb0 = (((cb0 & 3) ^ ((rb0 >> 1) & 3)) * 8);
    const int cb1 = t + 256, rb1 = cb1 >> 2, sb1 = (((cb1 & 3) ^ ((rb1 >> 1) & 3)) * 8);
    const bool bex = (t < 128);

    f32x4 acc[4][3] = {};

#define STG_P(k0_, buf)                                                                \
    {                                                                                  \
        _Float16* ab = &As[(buf)][0][0];                                               \
        _Float16* bb = &Bs[(buf)][0][0];                                               \
        _Pragma("unroll") for (int i = 0; i < 2; i++)                                  \
            glds16(A + (size_t)(bm + car[i]) * K + (k0_) + cas[i], ab + (t + i * 256) * 8); \
        glds16(B + (size_t)(bn + rb0) * K + (k0_) + sb0, bb + cb0 * 8);                \
        if (bex) glds16(B + (size_t)(bn + rb1) * K + (k0_) + sb1, bb + cb1 * 8);       \
    }

    STG_P(0, 0)

    int cur = 0;
    for (int k0 = 0; k0 < K; k0 += 32) {
        __syncthreads();
        if (k0 + 32 < K) STG_P(k0 + 32, cur ^ 1)
        h8 af[4], bf[3];
#pragma unroll
        for (int m = 0; m < 4; m++) {
            const int row = wy * 64 + m * 16 + l15;
            af[m] = ld8h(&As[cur][row][(l4 ^ ((row >> 1) & 3)) * 8]);
        }
#pragma unroll
        for (int n = 0; n < 3; n++) {
            const int row = wx * 48 + n * 16 + l15;
            bf[n] = ld8h(&Bs[cur][row][(l4 ^ ((row >> 1) & 3)) * 8]);
        }
#pragma unroll
        for (int m = 0; m < 4; m++)
#pragma unroll
            for (int n = 0; n < 3; n++)
                acc[m][n] = __builtin_amdgcn_mfma_f32_16x16x32_f16(af[m], bf[n], acc[m][n], 0, 0, 0);
        cur ^= 1;
    }
#undef STG_P

#pragma unroll
    for (int m = 0; m < 4; m++)
#pragma unroll
        for (int n = 0; n < 3; n++)
#pragma unroll
            for (int r = 0; r < 4; r++)
                C[(size_t)(bm + wy * 64 + m * 16 + l4 * 4 + r) * N + bn + wx * 48 + n * 16 + l15] =
                    acc[m][n][r];
}

// ---------------------------------------------------------------------------
// Flash attention, fp16 MFMA, diagonal-paired (uniform 17 tiles/phase-pair).
// 512 thr = 8 waves x 16 q-rows, KV tiles 64, dbuf + async reg-staging.
// Softmax in exp2 domain (log2e pre-folded into Q). Screened max-reduce:
// per-lane local max first; full shfl-reduce + rescale only when some lane's
// local max exceeds m+T (exact: if no lane exceeds, row max doesn't either).
// No setprio (lockstep-barrier regime: m190 showed it hurts there).
// ---------------------------------------------------------------------------
__global__ __launch_bounds__(512, 2) void attn_mfma(
    const _Float16* __restrict__ Qh, const _Float16* __restrict__ Kh,
    const _Float16* __restrict__ Vt, _Float16* __restrict__ Oh) {
    __shared__ _Float16 Ks[2][64][104];
    __shared__ _Float16 Vs[2][96][72];
    __shared__ _Float16 Ps[8][16][72];

    const float T2 = 11.5416f;  // 8 * log2(e): P bounded by e^8

    const int h = blockIdx.y;
    const int t = threadIdx.x, lane = t & 63, w = t >> 6;
    const int l15 = lane & 15, l4 = lane >> 4;

    const _Float16* Kg = Kh + (size_t)h * 2048 * 96;
    const _Float16* Vg = Vt + (size_t)h * 96 * 2048;

    const int cA = t, rKA = cA / 12, sKA = (cA % 12) * 8;
    const int rVA = cA >> 3, sVA = (cA & 7) * 8;
    const int cB = 512 + t, rKB = cB / 12, sKB = (cB % 12) * 8;
    const int rVB = cB >> 3, sVB = (cB & 7) * 8;
    const bool two = (t < 256);

    for (int ph = 0; ph < 2; ph++) {
        const int qt = ph ? (int)blockIdx.x : 15 - (int)blockIdx.x;
        const int q0 = qt * 128;
        const int wq = q0 + w * 16;

        h8 qf[3];
        const size_t qrow = ((size_t)h * 2048 + wq + l15) * 96;
#pragma unroll
        for (int kc = 0; kc < 3; kc++) qf[kc] = ld8h(Qh + qrow + kc * 32 + l4 * 8);

        us8 kregA, vregA, kregB, vregB;
        kregA = *(const us8*)(Kg + (size_t)rKA * 96 + sKA);
        vregA = *(const us8*)(Vg + (size_t)rVA * 2048 + sVA);
        if (two) {
            kregB = *(const us8*)(Kg + (size_t)rKB * 96 + sKB);
            vregB = *(const us8*)(Vg + (size_t)rVB * 2048 + sVB);
        }

        f32x4 o[6] = {};
        float m_i[4] = {-1e30f, -1e30f, -1e30f, -1e30f};
        float l_i[4] = {0.f, 0.f, 0.f, 0.f};

        const int nkt = 2 * qt + 2;
        for (int kt = 0; kt < nkt; kt++) {
            const int kv0 = kt * 64;
            const int buf = kt & 1;
            *(us8*)&Ks[buf][rKA][sKA] = kregA;
            *(us8*)&Vs[buf][rVA][sVA] = vregA;
            if (two) {
                *(us8*)&Ks[buf][rKB][sKB] = kregB;
                *(us8*)&Vs[buf][rVB][sVB] = vregB;
            }
            __syncthreads();
            if (kt + 1 < nkt) {  // prefetch next tile into regs (T14)
                const int kv1 = kv0 + 64;
                kregA = *(const us8*)(Kg + (size_t)(kv1 + rKA) * 96 + sKA);
                vregA = *(const us8*)(Vg + (size_t)rVA * 2048 + kv1 + sVA);
                if (two) {
                    kregB = *(const us8*)(Kg + (size_t)(kv1 + rKB) * 96 + sKB);
                    vregB = *(const us8*)(Vg + (size_t)rVB * 2048 + kv1 + sVB);
                }
            }

            if (kv0 <= wq + 15) {  // tile visible to this wave
                f32x4 s[4] = {};
#pragma unroll
                for (int f = 0; f < 4; f++)
#pragma unroll
                    for (int kc = 0; kc < 3; kc++) {
                        h8 kf = ld8h(&Ks[buf][f * 16 + l15][kc * 32 + l4 * 8]);
                        s[f] = __builtin_amdgcn_mfma_f32_16x16x32_f16(qf[kc], kf, s[f], 0, 0, 0);
                    }

                if (kv0 + 63 > wq) {  // diagonal-crossing: causal mask
#pragma unroll
                    for (int f = 0; f < 4; f++)
#pragma unroll
                        for (int r = 0; r < 4; r++)
                            if (kv0 + f * 16 + l15 > wq + l4 * 4 + r) s[f][r] = -1e30f;
                }

                // screened max: per-lane local max first (no shfl in common path)
                float lm[4];
                bool need = false;
#pragma unroll
                for (int r = 0; r < 4; r++) {
                    lm[r] = fmaxf(fmaxf(s[0][r], s[1][r]), fmaxf(s[2][r], s[3][r]));
                    need = need || (lm[r] > m_i[r] + T2);
                }
                if (__any(need)) {  // full row-max reduce + rescale (rare)
#pragma unroll
                    for (int r = 0; r < 4; r++) {
                        float m0 = lm[r];
#pragma unroll
                        for (int msk = 1; msk < 16; msk <<= 1) m0 = fmaxf(m0, __shfl_xor(m0, msk, 64));
                        const float mnew = fmaxf(m_i[r], m0);
                        const float sc = exp2f(m_i[r] - mnew);
                        m_i[r] = mnew;
                        l_i[r] *= sc;
#pragma unroll
                        for (int f2 = 0; f2 < 6; f2++) o[f2][r] *= sc;
                    }
                }

#pragma unroll
                for (int f = 0; f < 4; f++)
#pragma unroll
                    for (int r = 0; r < 4; r++) {
                        const float p = exp2f(s[f][r] - m_i[r]);
                        Ps[w][l4 * 4 + r][f * 16 + l15] = (_Float16)p;
                        l_i[r] += p;  // per-lane partial; reduced in epilogue
                    }
#pragma unroll
                for (int kc2 = 0; kc2 < 2; kc2++) {
                    h8 pa = ld8h(&Ps[w][l15][kc2 * 32 + l4 * 8]);
#pragma unroll
                    for (int f2 = 0; f2 < 6; f2++) {
                        h8 vb = ld8h(&Vs[buf][f2 * 16 + l15][kc2 * 32 + l4 * 8]);
                        o[f2] = __builtin_amdgcn_mfma_f32_16x16x32_f16(pa, vb, o[f2], 0, 0, 0);
                    }
                }
            }
        }

        __syncthreads();  // all waves done with LDS before next phase restages

#pragma unroll
        for (int r = 0; r < 4; r++) {
            float ss = l_i[r];
#pragma unroll
            for (int msk = 1; msk < 16; msk <<= 1) ss += __shfl_xor(ss, msk, 64);
            const float inv = 1.0f / ss;
            const size_t row = (size_t)(wq + l4 * 4 + r) * 3072 + h * 96;
#pragma unroll
            for (int f2 = 0; f2 < 6; f2++)
                Oh[row + f2 * 16 + l15] = (_Float16)(o[f2][r] * inv);
        }
    }
}

// ---------------------------------------------------------------------------
extern "C" void kernel_launch(void* const* d_in, const int* in_sizes, int n_in,
                              void* d_out, int out_size, void* d_ws, size_t ws_size,
                              hipStream_t stream) {
    const float* x = (const float*)d_in[0];
    const float* w_qkv = (const float*)d_in[1];
    const float* w_o = (const float*)d_in[2];
    const float* sf = (const float*)d_in[3];
    float* out = (float*)d_out;
    char* ws = (char*)d_ws;

    _Float16* wqkvh = (_Float16*)(ws);             // [0, 56.6MB)
    _Float16* Qh = (_Float16*)(ws + 56623104);
    _Float16* Kh = (_Float16*)(ws + 69206016);
    _Float16* Vth = (_Float16*)(ws + 81788928);
    _Float16* Oh = (_Float16*)(ws + 94371840);
    _Float16* xh = (_Float16*)(ws + 132120576);
    _Float16* woh = (_Float16*)(ws + 144703488);
    float* cs = (float*)(ws + 163577856);
    float* sn = (float*)(ws + 163971072);

    const float rope_scale = (float)sqrt(1.0 + log(131072.0 / 4096.0) / log(4096.0));
    // attn_scale * log2(e): attention computes exp2 directly
    const float q_scale = (float)((1.0 / sqrt(96.0)) * 1.4426950408889634);

    convert_half<<<3072, 256, 0, stream>>>(x, xh, 786432);
    convert_half<<<13824, 256, 0, stream>>>(w_qkv, wqkvh, 3538944);
    rope_table<<<384, 256, 0, stream>>>(sf, cs, sn, rope_scale);
    gemm_qkv<<<dim3(48, 16), 256, 0, stream>>>(xh, wqkvh, cs, sn, Qh, Kh, Vth, q_scale);
    convert_half<<<4608, 256, 0, stream>>>(w_o, woh, 1179648);
    attn_mfma<<<dim3(8, 32), 512, 0, stream>>>(Qh, Kh, Vth, Oh);
    gemm_p<<<dim3(32, 16), 256, 0, stream>>>(Oh, woh, out, 2048, 3072, 3072);
}